// Round 8
// baseline (131.132 us; speedup 1.0000x reference)
//
#include <hip/hip_runtime.h>
#include <math.h>

typedef unsigned long long u64;
typedef unsigned int u32;
typedef unsigned char u8;
typedef unsigned short u16;

#define HH 512
#define WW 512
#define NIMG 96
#define NB 5

__global__ __launch_bounds__(64) void k_zero(int* __restrict__ c) {
    if (threadIdx.x < 32) c[threadIdx.x] = 0;
}

// =======================================================================
// A: sobel + NMS + thresholds -> u64 bitboards. LDS-free register sweep.
// One wave owns a full 512-wide row span; lane <-> col (lane + 64*j).
// Rolling registers: D (right-left), H ([1,2,1] row sum), mag, ml/mr
// (packed u16), 2-bit direction codes. Horizontal exchange: ds_bpermute
// of packed bytes/u16 + v_perm extraction with per-lane selectors.
// __ballot(e) directly yields the contiguous bitboard words.
// =======================================================================

#define LOADROW(y, f) {                                                     \
    int py_ = (y); py_ = py_ < 0 ? 0 : (py_ > HH - 1 ? HH - 1 : py_);       \
    const float* rp_ = img + (size_t)py_ * WW;                              \
    _Pragma("unroll") for (int j = 0; j < 8; ++j) f[j] = rp_[lane + 64 * j]; }

// D/H for one row from its 8 floats
#define DHROW(f, Dd, Hd) {                                                  \
    u32 q_[8];                                                              \
    _Pragma("unroll") for (int j = 0; j < 8; ++j) q_[j] = (u32)(f[j] * 255.0f); \
    u32 pk0_ = q_[0] | (q_[1] << 8) | (q_[2] << 16) | (q_[3] << 24);        \
    u32 pk1_ = q_[4] | (q_[5] << 8) | (q_[6] << 16) | (q_[7] << 24);        \
    u32 bl0_ = (u32)__builtin_amdgcn_ds_bpermute(bpDn, (int)pk0_);          \
    u32 bl1_ = (u32)__builtin_amdgcn_ds_bpermute(bpDn, (int)pk1_);          \
    u32 br0_ = (u32)__builtin_amdgcn_ds_bpermute(bpUp, (int)pk0_);          \
    u32 br1_ = (u32)__builtin_amdgcn_ds_bpermute(bpUp, (int)pk1_);          \
    _Pragma("unroll") for (int j = 0; j < 8; ++j) {                         \
        u32 selL_ = (j == 0) ? sPixL0 : (0x0c0c0c00u + (u32)j + dL);        \
        u32 selR_ = (j == 7) ? sPixR7 : (0x0c0c0c00u + (u32)j + dR);        \
        u32 lb_ = __builtin_amdgcn_perm(bl1_, bl0_, selL_);                 \
        u32 rb_ = __builtin_amdgcn_perm(br1_, br0_, selR_);                 \
        if (j == 0 && l0)  lb_ = q_[0];   /* replicate col 0   */           \
        if (j == 7 && l63) rb_ = q_[7];   /* replicate col 511 */           \
        Dd[j] = (int)rb_ - (int)lb_;                                        \
        Hd[j] = (int)(lb_ + rb_ + 2u * q_[j]);                              \
    } }

// mag/mlr/code for row ym from D/H rows ym-1..ym+1
#define MAGROW(ym, Da, Db, Dc, Ha, Hc, mgd, mlrd, codeD) {                  \
    codeD = 0;                                                              \
    int mt_[8];                                                             \
    if ((unsigned)(ym) < (unsigned)HH) {                                    \
        _Pragma("unroll") for (int j = 0; j < 8; ++j) {                     \
            int gx_ = Da[j] + 2 * Db[j] + Dc[j];                            \
            int gy_ = Hc[j] - Ha[j];                                        \
            int uu_ = gx_ < 0 ? -gx_ : gx_;                                 \
            int vv_ = gy_ < 0 ? -gy_ : gy_;                                 \
            int mag_ = uu_ + vv_;                                           \
            int aa_ = (gy_ < 0) ? -gx_ : gx_;                               \
            int qq_ = vv_ - uu_;                                            \
            int t2_ = 2 * uu_ * uu_;                                        \
            int c_ = (aa_ > 0) ? 1 : 3;                                     \
            if (qq_ > 0 && qq_ * qq_ > t2_) c_ = 2;                         \
            if (mag_ * mag_ < t2_) c_ = 0;                                  \
            mt_[j] = mag_;                                                  \
            codeD |= (u32)c_ << (2 * j);                                    \
        }                                                                   \
    } else {                                                                \
        _Pragma("unroll") for (int j = 0; j < 8; ++j) mt_[j] = 0;           \
    }                                                                       \
    u32 bm0_ = (u32)mt_[0] | ((u32)mt_[1] << 16);                           \
    u32 bm1_ = (u32)mt_[2] | ((u32)mt_[3] << 16);                           \
    u32 bm2_ = (u32)mt_[4] | ((u32)mt_[5] << 16);                           \
    u32 bm3_ = (u32)mt_[6] | ((u32)mt_[7] << 16);                           \
    u32 L0_ = (u32)__builtin_amdgcn_ds_bpermute(bpDn, (int)bm0_);           \
    u32 L1_ = (u32)__builtin_amdgcn_ds_bpermute(bpDn, (int)bm1_);           \
    u32 L2_ = (u32)__builtin_amdgcn_ds_bpermute(bpDn, (int)bm2_);           \
    u32 L3_ = (u32)__builtin_amdgcn_ds_bpermute(bpDn, (int)bm3_);           \
    u32 R0_ = (u32)__builtin_amdgcn_ds_bpermute(bpUp, (int)bm0_);           \
    u32 R1_ = (u32)__builtin_amdgcn_ds_bpermute(bpUp, (int)bm1_);           \
    u32 R2_ = (u32)__builtin_amdgcn_ds_bpermute(bpUp, (int)bm2_);           \
    u32 R3_ = (u32)__builtin_amdgcn_ds_bpermute(bpUp, (int)bm3_);           \
    u32 ml_[8], mr_[8];                                                     \
    ml_[0] = __builtin_amdgcn_perm(L0_, L0_, sML_j0);                       \
    ml_[1] = __builtin_amdgcn_perm(L0_, L0_, sML_odd);                      \
    ml_[2] = __builtin_amdgcn_perm(L1_, L0_, sML_even);                     \
    ml_[3] = __builtin_amdgcn_perm(L1_, L1_, sML_odd);                      \
    ml_[4] = __builtin_amdgcn_perm(L2_, L1_, sML_even);                     \
    ml_[5] = __builtin_amdgcn_perm(L2_, L2_, sML_odd);                      \
    ml_[6] = __builtin_amdgcn_perm(L3_, L2_, sML_even);                     \
    ml_[7] = __builtin_amdgcn_perm(L3_, L3_, sML_odd);                      \
    mr_[0] = __builtin_amdgcn_perm(R0_, R0_, sMR_even);                     \
    mr_[1] = __builtin_amdgcn_perm(R1_, R0_, sMR_odd);                      \
    mr_[2] = __builtin_amdgcn_perm(R1_, R1_, sMR_even);                     \
    mr_[3] = __builtin_amdgcn_perm(R2_, R1_, sMR_odd);                      \
    mr_[4] = __builtin_amdgcn_perm(R2_, R2_, sMR_even);                     \
    mr_[5] = __builtin_amdgcn_perm(R3_, R2_, sMR_odd);                      \
    mr_[6] = __builtin_amdgcn_perm(R3_, R3_, sMR_even);                     \
    mr_[7] = __builtin_amdgcn_perm(R3_, R3_, sMR_j7);                       \
    _Pragma("unroll") for (int j = 0; j < 8; ++j) {                         \
        mgd[j] = mt_[j];                                                    \
        mlrd[j] = ml_[j] | (mr_[j] << 16);                                  \
    } }

__global__ __launch_bounds__(256, 3) void k_sobel_bits(const float* __restrict__ in,
                                                       u64* __restrict__ Wg,
                                                       u64* __restrict__ Eg) {
    const int tid = threadIdx.x, wv = tid >> 6, lane = tid & 63;
    const int bid = blockIdx.x, z = bid >> 3, Bb = bid & 7;
    const int Y0 = Bb * 64 + wv * 16;
    const float* img = in + (size_t)z * (HH * WW);

    const int bpDn = ((lane + 63) & 63) << 2;   // lane-1 (wrap)
    const int bpUp = ((lane + 1) & 63) << 2;    // lane+1 (wrap)
    const bool l0 = (lane == 0), l63 = (lane == 63);
    const u32 dL = l0 ? (u32)-1 : 0u;
    const u32 dR = l63 ? 1u : 0u;
    const u32 sPixL0 = l0 ? 0x0c0c0c0cu : 0x0c0c0c00u;   // j=0 (l0 overridden)
    const u32 sPixR7 = l63 ? 0x0c0c0c0cu : 0x0c0c0c07u;  // j=7 (l63 overridden)
    const u32 sML_j0   = l0  ? 0x0c0c0c0cu : 0x0c0c0100u;
    const u32 sML_odd  = l0  ? 0x0c0c0100u : 0x0c0c0302u;
    const u32 sML_even = l0  ? 0x0c0c0302u : 0x0c0c0504u;
    const u32 sMR_even = l63 ? 0x0c0c0302u : 0x0c0c0100u;
    const u32 sMR_odd  = l63 ? 0x0c0c0504u : 0x0c0c0302u;
    const u32 sMR_j7   = l63 ? 0x0c0c0c0cu : 0x0c0c0302u;

    // store lanes: 0-7 -> strong plane word (lane), 8-15 -> weak plane
    const int sj = lane & 7;
    u64* sptr;
    {
        u64* pl = (lane < 8) ? Eg : Wg;
        size_t sb = ((size_t)(z * 16 + (Y0 >> 7) * 4 + (sj >> 1)) * 256
                     + (size_t)(Y0 & 127) * 2 + (sj & 1));
        sptr = pl + sb;
    }

    int D[3][8], Hs[3][8], mg[3][8];
    u32 mlr[3][8];
    u32 codeP, codeC, codeJ;
    float fA[8], fB[8];

    // ---------------- prologue: rows Y0-2 .. Y0+2
    {
        float f0[8], f1[8], f2[8], f3[8];
        LOADROW(Y0 - 2, f0);
        LOADROW(Y0 - 1, f1);
        LOADROW(Y0,     f2);
        LOADROW(Y0 + 1, f3);
        LOADROW(Y0 + 2, fA);
        int Dm2[8], Hm2[8], Dm1[8], Hm1[8];
        DHROW(f0, Dm2, Hm2);
        DHROW(f1, Dm1, Hm1);
        DHROW(f2, D[0], Hs[0]);   // row Y0
        DHROW(f3, D[1], Hs[1]);   // row Y0+1
        MAGROW(Y0 - 1, Dm2, Dm1, D[0], Hm2, Hs[0], mg[0], mlr[0], codeJ);
        MAGROW(Y0,     Dm1, D[0], D[1], Hm1, Hs[1], mg[1], mlr[1], codeP);
        (void)codeJ;
    }

    // ---------------- main sweep: classify rows Y0 .. Y0+15
    #pragma unroll 1
    for (int i = 0; i < 16; ++i) {
        const int r = Y0 + i;
        if (i < 15) LOADROW(r + 3, fB);
        DHROW(fA, D[2], Hs[2]);                                   // row r+2
        MAGROW(r + 1, D[0], D[1], D[2], Hs[0], Hs[2], mg[2], mlr[2], codeC);

        // classify row r -> ballots -> store words
        {
            u64 BE[8], BW[8];
            #pragma unroll
            for (int j = 0; j < 8; ++j) {
                int c = (int)((codeP >> (2 * j)) & 3u);
                int m0 = mg[1][j];
                int ml1v = (int)(mlr[1][j] & 0xffffu), mr1v = (int)(mlr[1][j] >> 16);
                int ml2v = (int)(mlr[2][j] & 0xffffu), mr2v = (int)(mlr[2][j] >> 16);
                int ml0v = (int)(mlr[0][j] & 0xffffu), mr0v = (int)(mlr[0][j] >> 16);
                int n1 = (c == 0) ? mr1v : (c == 1) ? mr2v : (c == 2) ? mg[2][j] : ml2v;
                int n2 = (c == 0) ? ml1v : (c == 1) ? ml0v : (c == 2) ? mg[0][j] : mr0v;
                int nm = n1 > n2 ? n1 : n2;
                bool e = (m0 > 50) && (m0 >= nm);
                bool st = e && (m0 > 150);
                BW[j] = __ballot(e);
                BE[j] = __ballot(st);
            }
            u64 val = 0;
            #pragma unroll
            for (int k = 0; k < 8; ++k) {
                val = (lane == k) ? BE[k] : val;
                val = (lane == 8 + k) ? BW[k] : val;
            }
            if (lane < 16) *sptr = val;
            sptr += 2;
        }

        // roll state
        #pragma unroll
        for (int j = 0; j < 8; ++j) {
            D[0][j] = D[1][j];   D[1][j] = D[2][j];
            Hs[0][j] = Hs[1][j]; Hs[1][j] = Hs[2][j];
            mg[0][j] = mg[1][j]; mg[1][j] = mg[2][j];
            mlr[0][j] = mlr[1][j]; mlr[1][j] = mlr[2][j];
            fA[j] = fB[j];
        }
        codeP = codeC;
    }
}

// =================== proven bit-domain hysteresis tail ===================

#define CONVERGE()                                                          \
    for (;;) {                                                              \
        if (tid == 0) s_any = 0;                                            \
        __syncthreads();                                                    \
        for (int slot = tid; slot < 260; slot += 256) {                     \
            int row_ = slot >> 1, w_ = slot & 1;                            \
            u64 E = Eb[row_][w_], Eo = Eb[row_][w_ ^ 1];                    \
            u64 h = E | (E << 1) | (E >> 1);                                \
            if (w_ == 0) h |= (u64)hLE[row_] | ((Eo & 1ull) << 63);         \
            else         h |= (Eo >> 63) | (((u64)hRE[row_]) << 63);        \
            Hb[row_][w_] = h;                                               \
        }                                                                   \
        __syncthreads();                                                    \
        {                                                                   \
            int row_ = (tid >> 1) + 1, w_ = tid & 1;                        \
            u64 W = Wb[row_][w_], E = Eb[row_][w_];                         \
            u64 nb = Hb[row_ - 1][w_] | Hb[row_ + 1][w_] | Hb[row_][w_];    \
            u64 En = E | (W & nb);                                          \
            for (;;) {                                                      \
                u64 E2 = En | (W & ((En << 1) | (En >> 1)));                \
                if (E2 == En) break;                                        \
                En = E2;                                                    \
            }                                                               \
            if (En != E) { Eb[row_][w_] = En; s_any = 1; }                  \
        }                                                                   \
        __syncthreads();                                                    \
        int f_ = s_any;                                                     \
        __syncthreads();                                                    \
        if (!f_) break;                                                     \
    }

#define LOAD_BIT_TILE(LOADW)                                                \
    const int bid = blockIdx.x, z = bid >> 4, t4 = bid & 15;                \
    const int ty = t4 >> 2, tx = t4 & 3;                                    \
    const size_t base = (size_t)bid * 256;                                  \
    const int row = tid >> 1, w = tid & 1;                                  \
    u64 E0 = Eg[base + tid];                                                \
    Eb[row + 1][w] = E0;                                                    \
    if (LOADW) Wb[row + 1][w] = Wg[base + tid];                             \
    if (tid < 128) {                                                        \
        u64 e = 0;                                                          \
        if (tx > 0) e = Eg[base - 256 + (size_t)tid * 2 + 1];               \
        hLE[tid + 1] = (u8)(e >> 63);                                       \
    } else {                                                                \
        int r_ = tid - 128;                                                 \
        u64 e = 0;                                                          \
        if (tx < 3) e = Eg[base + 256 + (size_t)r_ * 2];                    \
        hRE[r_ + 1] = (u8)(e & 1);                                          \
    }                                                                       \
    if (tid < 2) {                                                          \
        u64 e = 0; if (ty > 0) e = Eg[base - 1024 + 254 + tid];             \
        Eb[0][tid] = e;                                                     \
    } else if (tid < 4) {                                                   \
        u64 e = 0; if (ty < 3) e = Eg[base + 1024 + (tid - 2)];             \
        Eb[129][tid - 2] = e;                                               \
    } else if (tid == 4) {                                                  \
        u64 e = 0; if (ty > 0 && tx > 0) e = Eg[base - 1280 + 255];         \
        hLE[0] = (u8)(e >> 63);                                             \
    } else if (tid == 5) {                                                  \
        u64 e = 0; if (ty > 0 && tx < 3) e = Eg[base - 768 + 254];          \
        hRE[0] = (u8)(e & 1);                                               \
    } else if (tid == 6) {                                                  \
        u64 e = 0; if (ty < 3 && tx > 0) e = Eg[base + 768 + 1];            \
        hLE[129] = (u8)(e >> 63);                                           \
    } else if (tid == 7) {                                                  \
        u64 e = 0; if (ty < 3 && tx < 3) e = Eg[base + 1280];               \
        hRE[129] = (u8)(e & 1);                                             \
    }

__global__ __launch_bounds__(256) void k_hystbit(u64* __restrict__ Wg, u64* __restrict__ Eg,
                                                 int* __restrict__ counters, int pass) {
    if (pass > 0 && counters[pass - 1] == 0) return;
    __shared__ u64 Wb[130][2], Eb[130][2], Hb[130][2];
    __shared__ u8 hLE[130], hRE[130];
    __shared__ int s_any, s_chg;
    const int tid = threadIdx.x;
    if (tid == 0) s_chg = 0;

    LOAD_BIT_TILE(1)
    __syncthreads();

    CONVERGE();

    u64 En = Eb[row + 1][w];
    if (En != E0) { Eg[base + tid] = En; s_chg = 1; }
    __syncthreads();
    if (tid == 0 && s_chg) atomicAdd(&counters[pass], 1);
}

__global__ __launch_bounds__(256) void k_hystbit_final(u64* __restrict__ Wg,
                                                       u64* __restrict__ Eg,
                                                       float* __restrict__ outf) {
    __shared__ u64 Wb[130][2], Eb[130][2], Hb[130][2];
    __shared__ u8 hLE[130], hRE[130];
    __shared__ int s_any;
    const int tid = threadIdx.x;

    LOAD_BIT_TILE(1)
    (void)E0;
    __syncthreads();

    CONVERGE();

    const int y0 = ty * 128, x0 = tx * 128;
    float4* op = (float4*)(outf + (size_t)z * (HH * WW));
    const int rg = tid >> 5, cl = tid & 31;
    #pragma unroll
    for (int k = 0; k < 16; ++k) {
        int r = rg + (k << 3);
        u64 E = Eb[r + 1][cl >> 4];
        int b0 = (cl << 2) & 63;
        float4 v;
        v.x = (float)((E >> b0) & 1ull);
        v.y = (float)((E >> (b0 + 1)) & 1ull);
        v.z = (float)((E >> (b0 + 2)) & 1ull);
        v.w = (float)((E >> (b0 + 3)) & 1ull);
        op[((size_t)(y0 + r) * WW + x0 + (cl << 2)) >> 2] = v;
    }
}

extern "C" void kernel_launch(void* const* d_in, const int* in_sizes, int n_in,
                              void* d_out, int out_size, void* d_ws, size_t ws_size,
                              hipStream_t stream) {
    const float* in = (const float*)d_in[0];
    float* out = (float*)d_out;
    int* counters = (int*)d_ws;

    k_zero<<<1, 64, 0, stream>>>(counters);

    const size_t bbwords = (size_t)NIMG * 16 * 128 * 2;   // u64 words per plane
    u64* Wg = (u64*)((char*)d_ws + 256);
    u64* Eg = Wg + bbwords;

    dim3 gA(NIMG * 8);                 // 768 blocks, 4 waves each (16-row sub-bands)
    k_sobel_bits<<<gA, 256, 0, stream>>>(in, Wg, Eg);

    dim3 gB(NIMG * 16);
    for (int p = 0; p < NB; ++p)
        k_hystbit<<<gB, 256, 0, stream>>>(Wg, Eg, counters, p);
    k_hystbit_final<<<gB, 256, 0, stream>>>(Wg, Eg, out);
}